// Round 1
// 972.471 us; speedup vs baseline: 1.0542x; 1.0542x over previous
//
#include <hip/hip_runtime.h>

// Problem constants
#define NLAT 192      // K (latitude rings)
#define MM   192      // zonal wavenumbers kept (M = TRUNC+1)
#define LL   192      // l dimension
#define PMAX 404      // max ring length
#define NGRID 41088
#define BC   1024     // BATCH*CHAN = 16*64
#define TWO_PI_F 6.2831853071795864769f

// Smallest ring index with nonzero basis for wavenumber m.
// nlon_k = 24 + 4k (k < 96), mirrored for k >= 96; nonzero iff m <= nlon/2.
__device__ __forceinline__ int kmin_of_m(int m) {
    return (m <= 12) ? 0 : ((m - 11) >> 1);
}

// ---------------------------------------------------------------------------
// Stage 1: per-ring DFT.  re/im[m][k][bc] = 2pi * sum_p x[bc][slon+p]*basis[k][p][m]
// Grid: (bcc/128, 3 m-tiles, 192 k).  Block 256.  128(bc) x 64(m) tile, 8x4 micro.
// Zero tiles (m0 > nlon/2) are written only where stage2's chunk-rounded
// k-loop can read them: k in [16*floor(kmin(m0)/16), 191 - same].
// ---------------------------------------------------------------------------
__global__ __launch_bounds__(256) void sht_stage1(
    const float* __restrict__ x,
    const float* __restrict__ cosb,
    const float* __restrict__ sinb,
    const int*   __restrict__ ring,
    float* __restrict__ ws,        // re at 0, im at MM*NLAT*bcc
    int bc0, int bcc)
{
    const int k   = blockIdx.z;
    const int m0  = blockIdx.y * 64;
    const int bct = blockIdx.x * 128;
    const int tid = threadIdx.x;
    const int tx  = tid & 15;                   // -> bc micro (4*tx+i, 64+4*tx+i)
    const int ty  = tid >> 4;                   // -> m  micro (4*ty+j)

    const int slon = ring[k * PMAX];
    const int nlon = ring[k * PMAX + PMAX - 1] - slon + 1;

    float* __restrict__ re_ws = ws;
    float* __restrict__ im_ws = ws + (size_t)MM * NLAT * bcc;

    if (m0 > (nlon >> 1)) {
        const int klo16 = kmin_of_m(m0) & ~15;
        if (k < klo16 || k > (NLAT - 1) - klo16) return;   // never read by stage2
        const float4 z = {0.f, 0.f, 0.f, 0.f};
#pragma unroll
        for (int j = 0; j < 4; ++j) {
            const int m = m0 + 4 * ty + j;
            const size_t base = ((size_t)m * NLAT + k) * bcc + bct;
            *(float4*)&re_ws[base + 4 * tx]      = z;
            *(float4*)&re_ws[base + 64 + 4 * tx] = z;
            *(float4*)&im_ws[base + 4 * tx]      = z;
            *(float4*)&im_ws[base + 64 + 4 * tx] = z;
        }
        return;
    }

    __shared__ float xs[16][128];   // [p][bc]
    __shared__ float cs[16][64];    // [p][m]
    __shared__ float ss[16][64];

    float accr[8][4] = {{0.f}};
    float acci[8][4] = {{0.f}};

    for (int p0 = 0; p0 < nlon; p0 += 16) {
        // x tile: 16p x 128bc = 512 float4 loads (float4 along p, contiguous).
#pragma unroll
        for (int r = 0; r < 2; ++r) {
            const int idx = r * 256 + tid;
            const int bl  = idx & 127;
            const int pq  = (idx >> 7) * 4;     // 0,4,8,12
            float4 v = {0.f, 0.f, 0.f, 0.f};
            if (p0 + pq < nlon)   // nlon, slon, p all multiples of 4 -> aligned, no straddle
                v = *(const float4*)(x + (size_t)(bc0 + bct + bl) * NGRID + slon + p0 + pq);
            xs[pq + 0][bl] = v.x;
            xs[pq + 1][bl] = v.y;
            xs[pq + 2][bl] = v.z;
            xs[pq + 3][bl] = v.w;
        }
        // basis tile: 16p x 64m, float4 along m.
        {
            const int mq = tx * 4;
            const int pl = ty;
            float4 c = {0.f, 0.f, 0.f, 0.f}, s = {0.f, 0.f, 0.f, 0.f};
            if (p0 + pl < PMAX) {
                const size_t off = ((size_t)k * PMAX + p0 + pl) * MM + m0 + mq;
                c = *(const float4*)(cosb + off);
                s = *(const float4*)(sinb + off);
            }
            *(float4*)&cs[pl][mq] = c;
            *(float4*)&ss[pl][mq] = s;
        }
        __syncthreads();

#pragma unroll
        for (int pp = 0; pp < 16; ++pp) {
            const float4 xa = *(const float4*)&xs[pp][4 * tx];
            const float4 xb = *(const float4*)&xs[pp][64 + 4 * tx];
            const float4 cv = *(const float4*)&cs[pp][4 * ty];
            const float4 sv = *(const float4*)&ss[pp][4 * ty];
            const float xv[8] = {xa.x, xa.y, xa.z, xa.w, xb.x, xb.y, xb.z, xb.w};
            const float cw[4] = {cv.x, cv.y, cv.z, cv.w};
            const float sw[4] = {sv.x, sv.y, sv.z, sv.w};
#pragma unroll
            for (int i = 0; i < 8; ++i)
#pragma unroll
                for (int j = 0; j < 4; ++j) {
                    accr[i][j] += xv[i] * cw[j];
                    acci[i][j] += xv[i] * sw[j];
                }
        }
        __syncthreads();
    }

#pragma unroll
    for (int j = 0; j < 4; ++j) {
        const int m = m0 + 4 * ty + j;
        const size_t base = ((size_t)m * NLAT + k) * bcc + bct;
        float4 r0 = {accr[0][j] * TWO_PI_F, accr[1][j] * TWO_PI_F,
                     accr[2][j] * TWO_PI_F, accr[3][j] * TWO_PI_F};
        float4 r1 = {accr[4][j] * TWO_PI_F, accr[5][j] * TWO_PI_F,
                     accr[6][j] * TWO_PI_F, accr[7][j] * TWO_PI_F};
        float4 i0 = {acci[0][j] * TWO_PI_F, acci[1][j] * TWO_PI_F,
                     acci[2][j] * TWO_PI_F, acci[3][j] * TWO_PI_F};
        float4 i1 = {acci[4][j] * TWO_PI_F, acci[5][j] * TWO_PI_F,
                     acci[6][j] * TWO_PI_F, acci[7][j] * TWO_PI_F};
        *(float4*)&re_ws[base + 4 * tx]      = r0;
        *(float4*)&re_ws[base + 64 + 4 * tx] = r1;
        *(float4*)&im_ws[base + 4 * tx]      = i0;
        *(float4*)&im_ws[base + 64 + 4 * tx] = i1;
    }
}

// ---------------------------------------------------------------------------
// Stage 2: ws2[m][l][bc] = sum_k interm[m][k][bc] * weight[m][l][k]
// Grid: (bcc/128, 3 l-tiles, 192 m).  Block 256.  128(bc) x 64(l) tile, 8x4 micro.
// The k-loop runs only over the nonzero band [klo16, 191-klo16] (chunk-rounded).
// Columns with l < m (weight identically 0) are not written; the transpose
// masks that region on output.
// ---------------------------------------------------------------------------
__global__ __launch_bounds__(256) void sht_stage2(
    const float* __restrict__ ws,
    float* __restrict__ ws2,
    const float* __restrict__ weight,
    int bcc)
{
    const int m   = blockIdx.z;
    const int l0  = blockIdx.y * 64;
    const int bct = blockIdx.x * 128;
    const int tid = threadIdx.x;
    const int tx  = tid & 15;                  // -> bc micro
    const int ty  = tid >> 4;                  // -> l micro

    if (l0 + 63 < m) return;                   // weight == 0 for whole tile

    const int klo16 = kmin_of_m(m) & ~15;
    const int kcnt  = NLAT - 2 * klo16;        // multiple of 16 (symmetric band)

    const float* __restrict__ re_ws = ws;
    const float* __restrict__ im_ws = ws + (size_t)MM * NLAT * bcc;

    __shared__ float rs[16][128];   // [k][bc]
    __shared__ float is_[16][128];
    __shared__ float wl[16][64];    // [k][l]

    float accr[8][4] = {{0.f}};
    float acci[8][4] = {{0.f}};

    for (int kc = 0; kc < kcnt; kc += 16) {
        const int k0 = klo16 + kc;
        {
            const int bl4 = (tid & 31) * 4;    // 32 lanes * float4 = 128 bc
            const int kk  = tid >> 5;          // 8 rows per pass
#pragma unroll
            for (int r = 0; r < 2; ++r) {
                const int row = kk + r * 8;
                const size_t off = ((size_t)m * NLAT + k0 + row) * bcc + bct + bl4;
                *(float4*)&rs[row][bl4]  = *(const float4*)&re_ws[off];
                *(float4*)&is_[row][bl4] = *(const float4*)&im_ws[off];
            }
        }
        {
            const int kk = tid & 15;
            const int lw = tid >> 4;
#pragma unroll
            for (int r = 0; r < 4; ++r) {
                const int lc = lw + r * 16;
                wl[kk][lc] = weight[((size_t)m * LL + l0 + lc) * NLAT + k0 + kk];
            }
        }
        __syncthreads();

#pragma unroll
        for (int kk = 0; kk < 16; ++kk) {
            const float4 ra = *(const float4*)&rs[kk][4 * tx];
            const float4 rb = *(const float4*)&rs[kk][64 + 4 * tx];
            const float4 ia = *(const float4*)&is_[kk][4 * tx];
            const float4 ib = *(const float4*)&is_[kk][64 + 4 * tx];
            const float4 wv = *(const float4*)&wl[kk][4 * ty];
            const float rv[8] = {ra.x, ra.y, ra.z, ra.w, rb.x, rb.y, rb.z, rb.w};
            const float iv[8] = {ia.x, ia.y, ia.z, ia.w, ib.x, ib.y, ib.z, ib.w};
            const float wq[4] = {wv.x, wv.y, wv.z, wv.w};
#pragma unroll
            for (int i = 0; i < 8; ++i)
#pragma unroll
                for (int j = 0; j < 4; ++j) {
                    accr[i][j] += rv[i] * wq[j];
                    acci[i][j] += iv[i] * wq[j];
                }
        }
        __syncthreads();
    }

    float* __restrict__ re2 = ws2;
    float* __restrict__ im2 = ws2 + (size_t)MM * LL * bcc;
#pragma unroll
    for (int j = 0; j < 4; ++j) {
        const int l = l0 + 4 * ty + j;
        if (l < m) continue;                   // zero region: never read as data
        const size_t base = ((size_t)m * LL + l) * bcc + bct;
        float4 r0 = {accr[0][j], accr[1][j], accr[2][j], accr[3][j]};
        float4 r1 = {accr[4][j], accr[5][j], accr[6][j], accr[7][j]};
        float4 i0 = {acci[0][j], acci[1][j], acci[2][j], acci[3][j]};
        float4 i1 = {acci[4][j], acci[5][j], acci[6][j], acci[7][j]};
        *(float4*)&re2[base + 4 * tx]      = r0;
        *(float4*)&re2[base + 64 + 4 * tx] = r1;
        *(float4*)&im2[base + 4 * tx]      = i0;
        *(float4*)&im2[base + 64 + 4 * tx] = i1;
    }
}

// ---------------------------------------------------------------------------
// Transpose: out[bc][l][m][2] = {re2[m][l][bc], im2[m][l][bc]}  (0 for m > l)
// Grid: (bcc/64, 3 m-tiles of 64, 192 l).  Block 256.
// Reads float4 along bc (256 B/row); writes float4 along m (256 B segments).
// ---------------------------------------------------------------------------
__global__ __launch_bounds__(256) void sht_transpose(
    const float* __restrict__ ws2,
    float* __restrict__ out,
    int bc0, int bcc)
{
    const int l   = blockIdx.z;
    const int m0  = blockIdx.y * 64;
    const int bct = blockIdx.x * 64;
    const int tid = threadIdx.x;

    __shared__ float tr[64][66];
    __shared__ float ti[64][66];

    const bool anynz = (m0 <= l);
    if (anynz) {
        const float* __restrict__ re2 = ws2;
        const float* __restrict__ im2 = ws2 + (size_t)MM * LL * bcc;
        const int bl4 = (tid & 15) * 4;        // 16 lanes * float4 = 64 bc
        const int mr  = tid >> 4;              // 16 m-rows per pass
#pragma unroll
        for (int r = 0; r < 4; ++r) {
            const int row = mr + r * 16;
            const size_t off = ((size_t)(m0 + row) * LL + l) * bcc + bct + bl4;
            *(float4*)&tr[row][bl4] = *(const float4*)&re2[off];
            *(float4*)&ti[row][bl4] = *(const float4*)&im2[off];
        }
    }
    __syncthreads();

    const int mq  = tid & 15;                  // -> float4 = 2 m values
    const int bcw = tid >> 4;                  // 16 bc per pass
#pragma unroll
    for (int r = 0; r < 4; ++r) {
        const int bcl = bcw + r * 16;
        const int bc  = bc0 + bct + bcl;
#pragma unroll
        for (int h = 0; h < 2; ++h) {
            const int ml = 32 * h + 2 * mq;    // local m (even)
            const int m  = m0 + ml;
            float4 v = {0.f, 0.f, 0.f, 0.f};
            if (anynz) {
                if (m <= l)     { v.x = tr[ml][bcl];     v.y = ti[ml][bcl]; }
                if (m + 1 <= l) { v.z = tr[ml + 1][bcl]; v.w = ti[ml + 1][bcl]; }
            }
            const size_t o = (((size_t)bc * LL + l) * MM + m) * 2;
            *(float4*)&out[o] = v;
        }
    }
}

// ---------------------------------------------------------------------------
extern "C" void kernel_launch(void* const* d_in, const int* in_sizes, int n_in,
                              void* d_out, int out_size, void* d_ws, size_t ws_size,
                              hipStream_t stream)
{
    const float* x      = (const float*)d_in[0];
    const float* weight = (const float*)d_in[1];
    const float* cosb   = (const float*)d_in[2];
    const float* sinb   = (const float*)d_in[3];
    const int*   ring   = (const int*)d_in[4];
    float* out = (float*)d_out;
    float* wsf = (float*)d_ws;

    // Need interm (2*M*K*bcc floats) + ws2 (2*M*L*bcc floats) per chunk.
    const size_t per_bc = 4ull * MM * NLAT * sizeof(float);
    int chunk = BC;
    while ((size_t)chunk * per_bc > ws_size && chunk > 128) chunk >>= 1;

    for (int bc0 = 0; bc0 < BC; bc0 += chunk) {
        float* ws2 = wsf + 2ull * MM * NLAT * chunk;
        dim3 grid1(chunk / 128, 3, NLAT);
        hipLaunchKernelGGL(sht_stage1, grid1, dim3(256), 0, stream,
                           x, cosb, sinb, ring, wsf, bc0, chunk);
        dim3 grid2(chunk / 128, 3, MM);
        hipLaunchKernelGGL(sht_stage2, grid2, dim3(256), 0, stream,
                           wsf, ws2, weight, chunk);
        dim3 grid3(chunk / 64, 3, LL);
        hipLaunchKernelGGL(sht_transpose, grid3, dim3(256), 0, stream,
                           ws2, out, bc0, chunk);
    }
}